// Round 1
// baseline (128.679 us; speedup 1.0000x reference)
//
#include <hip/hip_runtime.h>
#include <math.h>

#define BS 8
#define SEQ 1024
#define DIM 1024
#define FF 4096
#define NE 8
#define TOPK 2
#define NSLOT (BS*TOPK)   // 16 selections (b,j)
#define MAXM 8            // max selections per expert (top-2 indices distinct per batch)
#define NCHUNK 64

// ws layout in floats
#define WS_PARTIAL 0                                  // [BS][NCHUNK][DIM] = 524288
#define WS_LOGITS  (WS_PARTIAL + BS*NCHUNK*DIM)       // 64
#define WS_SELW    (WS_LOGITS + BS*NE)                // 16
#define WS_SELE    (WS_SELW + NSLOT)                  // 16 (ints)
#define WS_ACT     (WS_SELE + NSLOT)                  // [NSLOT][FF] = 65536
#define WS_Y       (WS_ACT + NSLOT*FF)                // [NSLOT][DIM] = 16384

__device__ __forceinline__ float dot4(float4 a, float4 b) {
    return a.x*b.x + a.y*b.y + a.z*b.z + a.w*b.w;
}

// ---- 1. partial sums over L for the sequence mean ----
__global__ __launch_bounds__(256) void kmean(const float4* __restrict__ h4,
                                             float4* __restrict__ part4) {
    const int c = blockIdx.x, b = blockIdx.y, t = threadIdx.x;
    const int LPER = SEQ / NCHUNK;  // 16
    const float4* p = h4 + ((size_t)b * SEQ + (size_t)c * LPER) * (DIM/4) + t;
    float4 a = make_float4(0.f, 0.f, 0.f, 0.f);
    #pragma unroll
    for (int i = 0; i < LPER; ++i) {
        float4 v = p[(size_t)i * (DIM/4)];
        a.x += v.x; a.y += v.y; a.z += v.z; a.w += v.w;
    }
    part4[((size_t)(b * NCHUNK + c)) * (DIM/4) + t] = a;
}

// ---- 2. reduce partials -> hbar, compute router logits ----
__global__ __launch_bounds__(256) void krouter(const float4* __restrict__ part4,
                                               const float4* __restrict__ rw4,
                                               float* __restrict__ logits_ws,
                                               float* __restrict__ out_logits) {
    const int b = blockIdx.x, t = threadIdx.x;
    const float4* p = part4 + (size_t)b * NCHUNK * (DIM/4) + t;
    float4 s = make_float4(0.f, 0.f, 0.f, 0.f);
    #pragma unroll 4
    for (int c = 0; c < NCHUNK; ++c) {
        float4 v = p[(size_t)c * (DIM/4)];
        s.x += v.x; s.y += v.y; s.z += v.z; s.w += v.w;
    }
    const float inv = 1.0f / (float)SEQ;
    s.x *= inv; s.y *= inv; s.z *= inv; s.w *= inv;

    __shared__ float red[4];
    const int wave = t >> 6, lane = t & 63;
    for (int e = 0; e < NE; ++e) {
        float4 w = rw4[(size_t)e * (DIM/4) + t];
        float pd = dot4(s, w);
        #pragma unroll
        for (int o = 32; o; o >>= 1) pd += __shfl_xor(pd, o);
        if (lane == 0) red[wave] = pd;
        __syncthreads();
        if (t == 0) {
            float l = red[0] + red[1] + red[2] + red[3];
            logits_ws[b * NE + e] = l;
            out_logits[b * NE + e] = l;
        }
        __syncthreads();
    }
}

// ---- 3. softmax + top-2 per batch ----
__global__ void ktopk(const float* __restrict__ logits,
                      float* __restrict__ selw, int* __restrict__ sele) {
    const int b = threadIdx.x;
    if (b >= BS) return;
    float l[NE];
    float mx = -1e30f;
    #pragma unroll
    for (int e = 0; e < NE; ++e) { l[e] = logits[b * NE + e]; mx = fmaxf(mx, l[e]); }
    float s = 0.f;
    #pragma unroll
    for (int e = 0; e < NE; ++e) { l[e] = expf(l[e] - mx); s += l[e]; }
    const float invs = 1.f / s;
    float v1 = -1.f, v2 = -1.f; int e1 = -1, e2 = -1;
    #pragma unroll
    for (int e = 0; e < NE; ++e) {
        float pe = l[e] * invs;
        if (pe > v1)      { v2 = v1; e2 = e1; v1 = pe; e1 = e; }
        else if (pe > v2) { v2 = pe; e2 = e; }
    }
    selw[b * 2 + 0] = v1; sele[b * 2 + 0] = e1;
    selw[b * 2 + 1] = v2; sele[b * 2 + 1] = e2;
}

// ---- 4. up/gate + SiLU for selected (expert, token) pairs ----
#define ROWS_UG 32
__global__ __launch_bounds__(256) void kupgate(const float* __restrict__ h,
                                               const float4* __restrict__ w1_4,
                                               const float4* __restrict__ w3_4,
                                               const int* __restrict__ sele,
                                               float* __restrict__ act) {
    const int e = blockIdx.y, tile = blockIdx.x, t = threadIdx.x;
    __shared__ int slots_s[MAXM];
    __shared__ int ms;
    __shared__ __align__(16) float x_s[MAXM][DIM];   // 32 KB
    if (t == 0) {
        int m = 0;
        for (int s = 0; s < NSLOT; ++s) if (sele[s] == e) slots_s[m++] = s;
        ms = m;
    }
    __syncthreads();
    const int m = ms;
    if (m == 0) return;

    // stage selected token vectors (position j of batch b)
    for (int ti = 0; ti < m; ++ti) {
        int s = slots_s[ti];
        int b = s >> 1, j = s & 1;
        const float4* src = (const float4*)(h + ((size_t)b * SEQ + j) * DIM);
        ((float4*)&x_s[ti][0])[t] = src[t];
    }
    __syncthreads();

    const int wave = t >> 6, lane = t & 63;
    for (int k = 0; k < ROWS_UG / 4; ++k) {          // 8 rows per wave
        const int row = tile * ROWS_UG + wave * (ROWS_UG / 4) + k;
        float up[MAXM], gt[MAXM];
        #pragma unroll
        for (int i = 0; i < MAXM; ++i) { up[i] = 0.f; gt[i] = 0.f; }
        const float4* w1r = w1_4 + ((size_t)e * FF + row) * (DIM/4) + lane;
        const float4* w3r = w3_4 + ((size_t)e * FF + row) * (DIM/4) + lane;
        #pragma unroll
        for (int it = 0; it < 4; ++it) {
            float4 a = w1r[it * 64];
            float4 c = w3r[it * 64];
            #pragma unroll
            for (int ti = 0; ti < MAXM; ++ti) {
                if (ti < m) {
                    float4 x = ((const float4*)&x_s[ti][0])[it * 64 + lane];
                    up[ti] += dot4(a, x);
                    gt[ti] += dot4(c, x);
                }
            }
        }
        #pragma unroll
        for (int ti = 0; ti < MAXM; ++ti) {
            if (ti < m) {
                float u = up[ti], g = gt[ti];
                #pragma unroll
                for (int o = 32; o; o >>= 1) { u += __shfl_xor(u, o); g += __shfl_xor(g, o); }
                if (lane == 0) {
                    float av = (u / (1.f + expf(-u))) * g;   // silu(up)*gate
                    act[(size_t)slots_s[ti] * FF + row] = av;
                }
            }
        }
    }
}

// ---- 5. down projection, scaled by routing weight ----
#define ROWS_DN 8
__global__ __launch_bounds__(256) void kdown(const float4* __restrict__ w2_4,
                                             const float* __restrict__ act,
                                             const int* __restrict__ sele,
                                             const float* __restrict__ selw,
                                             float* __restrict__ y) {
    const int e = blockIdx.y, tile = blockIdx.x, t = threadIdx.x;
    __shared__ int slots_s[MAXM];
    __shared__ int ms;
    __shared__ __align__(16) float a_s[MAXM][1024];  // 32 KB chunk of act
    if (t == 0) {
        int m = 0;
        for (int s = 0; s < NSLOT; ++s) if (sele[s] == e) slots_s[m++] = s;
        ms = m;
    }
    __syncthreads();
    const int m = ms;
    if (m == 0) return;

    const int wave = t >> 6, lane = t & 63;
    float acc[2][MAXM];
    #pragma unroll
    for (int r = 0; r < 2; ++r)
        #pragma unroll
        for (int i = 0; i < MAXM; ++i) acc[r][i] = 0.f;

    for (int kc = 0; kc < 4; ++kc) {                 // 4 chunks of 1024 over FF
        __syncthreads();
        for (int ti = 0; ti < m; ++ti) {
            int s = slots_s[ti];
            ((float4*)&a_s[ti][0])[t] =
                ((const float4*)(act + (size_t)s * FF + kc * 1024))[t];
        }
        __syncthreads();
        #pragma unroll
        for (int r = 0; r < 2; ++r) {
            const int row = tile * ROWS_DN + wave * 2 + r;
            const float4* w2r = w2_4 + ((size_t)e * DIM + row) * (FF/4) + kc * 256 + lane;
            #pragma unroll
            for (int it = 0; it < 4; ++it) {
                float4 w = w2r[it * 64];
                #pragma unroll
                for (int ti = 0; ti < MAXM; ++ti) {
                    if (ti < m) {
                        float4 x = ((const float4*)&a_s[ti][0])[it * 64 + lane];
                        acc[r][ti] += dot4(w, x);
                    }
                }
            }
        }
    }
    #pragma unroll
    for (int r = 0; r < 2; ++r) {
        const int row = tile * ROWS_DN + wave * 2 + r;
        #pragma unroll
        for (int ti = 0; ti < MAXM; ++ti) {
            if (ti < m) {
                float v = acc[r][ti];
                #pragma unroll
                for (int o = 32; o; o >>= 1) v += __shfl_xor(v, o);
                if (lane == 0) {
                    int s = slots_s[ti];
                    y[(size_t)s * DIM + row] = selw[s] * v;
                }
            }
        }
    }
}

// ---- 6. combine two selections per batch, broadcast across L ----
__global__ __launch_bounds__(256) void kbcast(const float4* __restrict__ y4,
                                              float4* __restrict__ out4) {
    const int b = blockIdx.y, lg = blockIdx.x, t = threadIdx.x;
    float4 y0 = y4[(size_t)(2 * b) * (DIM/4) + t];
    float4 y1 = y4[(size_t)(2 * b + 1) * (DIM/4) + t];
    float4 c = make_float4(y0.x + y1.x, y0.y + y1.y, y0.z + y1.z, y0.w + y1.w);
    size_t base = ((size_t)b * SEQ + (size_t)lg * 8) * (DIM/4) + t;
    #pragma unroll
    for (int i = 0; i < 8; ++i) out4[base + (size_t)i * (DIM/4)] = c;
}

extern "C" void kernel_launch(void* const* d_in, const int* in_sizes, int n_in,
                              void* d_out, int out_size, void* d_ws, size_t ws_size,
                              hipStream_t stream) {
    const float* h  = (const float*)d_in[0];
    const float* rw = (const float*)d_in[1];
    const float* w1 = (const float*)d_in[2];
    const float* w2 = (const float*)d_in[3];
    const float* w3 = (const float*)d_in[4];
    float* out = (float*)d_out;
    float* ws  = (float*)d_ws;

    float* part   = ws + WS_PARTIAL;
    float* logits = ws + WS_LOGITS;
    float* selw   = ws + WS_SELW;
    int*   sele   = (int*)(ws + WS_SELE);
    float* act    = ws + WS_ACT;
    float* y      = ws + WS_Y;
    float* out_logits = out + (size_t)BS * SEQ * DIM;

    kmean  <<<dim3(NCHUNK, BS), 256, 0, stream>>>((const float4*)h, (float4*)part);
    krouter<<<BS, 256, 0, stream>>>((const float4*)part, (const float4*)rw, logits, out_logits);
    ktopk  <<<1, 64, 0, stream>>>(logits, selw, sele);
    kupgate<<<dim3(FF / ROWS_UG, NE), 256, 0, stream>>>(h, (const float4*)w1, (const float4*)w3, sele, act);
    kdown  <<<dim3(DIM / ROWS_DN, NE), 256, 0, stream>>>((const float4*)w2, act, sele, selw, y);
    kbcast <<<dim3(SEQ / 8, BS), 256, 0, stream>>>((const float4*)y, (float4*)out);
}